// Round 1
// baseline (51.393 us; speedup 1.0000x reference)
//
#include <hip/hip_runtime.h>

#pragma clang fp contract(off)

typedef unsigned long long u64;

#define TOPK 5

// compare-exchange on u64 keys (ascending)
#define CE(x, y) do { if ((y) < (x)) { u64 _t = (x); (x) = (y); (y) = _t; } } while (0)

__global__ __launch_bounds__(256) void matcher_topk_kernel(
    const float* __restrict__ pred_box,  // [B, NP, 4]
    const float* __restrict__ gt_box,    // [B, NG, 4]
    int* __restrict__ out_pred,          // [B, NG*TOPK]
    int* __restrict__ out_gt,            // [B, NG*TOPK]
    int B, int NP, int NG)
{
    const int g    = blockIdx.x * 4 + (threadIdx.x >> 6);   // one wave per (b, m)
    const int lane = threadIdx.x & 63;
    const int total = B * NG;
    if (g >= total) return;
    const int b = g / NG;
    const int m = g - b * NG;

    const float4 gb = ((const float4*)gt_box)[b * NG + m];
    const float g_area = (gb.z - gb.x) * (gb.w - gb.y);

    // sorted ascending top-5 keys; key = (cost_bits<<32) | pred_idx  (cost>=0)
    u64 k0 = ~0ULL, k1 = ~0ULL, k2 = ~0ULL, k3 = ~0ULL, k4 = ~0ULL;

    const float4* pbase = (const float4*)pred_box + (size_t)b * NP;
    for (int p = lane; p < NP; p += 64) {
        const float4 pb = pbase[p];
        const float area_p = (pb.z - pb.x) * (pb.w - pb.y);
        const float cost_bbox = fabsf(pb.x - gb.x) + fabsf(pb.y - gb.y)
                              + fabsf(pb.z - gb.z) + fabsf(pb.w - gb.w);
        // intersection
        const float ltx = fmaxf(pb.x, gb.x), lty = fmaxf(pb.y, gb.y);
        const float rbx = fminf(pb.z, gb.z), rby = fminf(pb.w, gb.w);
        const float iw = fmaxf(rbx - ltx, 0.0f), ih = fmaxf(rby - lty, 0.0f);
        const float inter = iw * ih;
        const float uni = area_p + g_area - inter;
        const float iou = inter / uni;
        // enclosing box
        const float ex1 = fminf(pb.x, gb.x), ey1 = fminf(pb.y, gb.y);
        const float ex2 = fmaxf(pb.z, gb.z), ey2 = fmaxf(pb.w, gb.w);
        const float ew = fmaxf(ex2 - ex1, 0.0f), eh = fmaxf(ey2 - ey1, 0.0f);
        const float area_e = ew * eh;
        const float giou = iou - (area_e - uni) / area_e;
        const float cost = cost_bbox + (1.0f - giou);

        const u64 nk = ((u64)__float_as_uint(cost) << 32) | (unsigned)p;
        // sorted insertion (scanning order => equal keys impossible; strict <)
        if (nk < k4) {
            if (nk < k3) { k4 = k3;
                if (nk < k2) { k3 = k2;
                    if (nk < k1) { k2 = k1;
                        if (nk < k0) { k1 = k0; k0 = nk; }
                        else         { k1 = nk; }
                    } else { k2 = nk; }
                } else { k3 = nk; }
            } else { k4 = nk; }
        }
    }

    // wave butterfly: merge sorted 5-lists across all 64 lanes
    #pragma unroll
    for (int off = 1; off < 64; off <<= 1) {
        const u64 b0 = __shfl_xor(k0, off);
        const u64 b1 = __shfl_xor(k1, off);
        const u64 b2 = __shfl_xor(k2, off);
        const u64 b3 = __shfl_xor(k3, off);
        const u64 b4 = __shfl_xor(k4, off);
        // lower half of bitonic merge: smallest 5 of union, bitonic sequence
        u64 m0 = k0 < b4 ? k0 : b4;
        u64 m1 = k1 < b3 ? k1 : b3;
        u64 m2 = k2 < b2 ? k2 : b2;
        u64 m3 = k3 < b1 ? k3 : b1;
        u64 m4 = k4 < b0 ? k4 : b0;
        // 5-element sorting network (9 CEs)
        CE(m0, m1); CE(m3, m4); CE(m2, m4); CE(m2, m3); CE(m1, m4);
        CE(m0, m3); CE(m0, m2); CE(m1, m3); CE(m1, m2);
        k0 = m0; k1 = m1; k2 = m2; k3 = m3; k4 = m4;
    }

    if (lane == 0) {
        const int base = (b * NG + m) * TOPK;
        out_pred[base + 0] = (int)(unsigned)(k0 & 0xFFFFFFFFu);
        out_pred[base + 1] = (int)(unsigned)(k1 & 0xFFFFFFFFu);
        out_pred[base + 2] = (int)(unsigned)(k2 & 0xFFFFFFFFu);
        out_pred[base + 3] = (int)(unsigned)(k3 & 0xFFFFFFFFu);
        out_pred[base + 4] = (int)(unsigned)(k4 & 0xFFFFFFFFu);
        out_gt[base + 0] = m;
        out_gt[base + 1] = m;
        out_gt[base + 2] = m;
        out_gt[base + 3] = m;
        out_gt[base + 4] = m;
    }
}

extern "C" void kernel_launch(void* const* d_in, const int* in_sizes, int n_in,
                              void* d_out, int out_size, void* d_ws, size_t ws_size,
                              hipStream_t stream) {
    const float* pred_box = (const float*)d_in[0];   // [B, NP, 4]
    const float* gt_box   = (const float*)d_in[2];   // [B, NG, 4]

    const int NP = 5000;
    const int B  = in_sizes[1] / NP;                 // pred_obj is [B, NP]
    const int NG = in_sizes[3] / B;                  // gt_obj is [B, NG]

    int* out_pred = (int*)d_out;
    int* out_gt   = out_pred + B * NG * TOPK;

    const int total = B * NG;                        // one wave per task
    const int blocks = (total + 3) / 4;              // 4 waves per 256-thread block
    hipLaunchKernelGGL(matcher_topk_kernel, dim3(blocks), dim3(256), 0, stream,
                       pred_box, gt_box, out_pred, out_gt, B, NP, NG);
}

// Round 2
// 42.500 us; speedup vs baseline: 1.2092x; 1.2092x over previous
//
#include <hip/hip_runtime.h>

#pragma clang fp contract(off)

typedef unsigned long long u64;

#define TOPK 5
#define WAVES 4   // waves per block; one block per (b, gt) task

// compare-exchange on u64 keys (ascending)
#define CE(x, y) do { if ((y) < (x)) { u64 _t = (x); (x) = (y); (y) = _t; } } while (0)

__device__ __forceinline__ u64 make_key(const float4 pb, const float4 gb,
                                        const float g_area, const int p) {
    const float area_p = (pb.z - pb.x) * (pb.w - pb.y);
    const float cost_bbox = fabsf(pb.x - gb.x) + fabsf(pb.y - gb.y)
                          + fabsf(pb.z - gb.z) + fabsf(pb.w - gb.w);
    // intersection
    const float ltx = fmaxf(pb.x, gb.x), lty = fmaxf(pb.y, gb.y);
    const float rbx = fminf(pb.z, gb.z), rby = fminf(pb.w, gb.w);
    const float iw = fmaxf(rbx - ltx, 0.0f), ih = fmaxf(rby - lty, 0.0f);
    const float inter = iw * ih;
    const float uni = area_p + g_area - inter;
    const float iou = inter / uni;
    // enclosing box
    const float ex1 = fminf(pb.x, gb.x), ey1 = fminf(pb.y, gb.y);
    const float ex2 = fmaxf(pb.z, gb.z), ey2 = fmaxf(pb.w, gb.w);
    const float ew = fmaxf(ex2 - ex1, 0.0f), eh = fmaxf(ey2 - ey1, 0.0f);
    const float area_e = ew * eh;
    const float giou = iou - (area_e - uni) / area_e;
    const float cost = cost_bbox + (1.0f - giou);
    return ((u64)__float_as_uint(cost) << 32) | (unsigned)p;
}

#define INSERT(nk)                                              \
    do { if ((nk) < k4) {                                       \
        if ((nk) < k3) { k4 = k3;                               \
            if ((nk) < k2) { k3 = k2;                           \
                if ((nk) < k1) { k2 = k1;                       \
                    if ((nk) < k0) { k1 = k0; k0 = (nk); }      \
                    else           { k1 = (nk); }               \
                } else { k2 = (nk); }                           \
            } else { k3 = (nk); }                               \
        } else { k4 = (nk); }                                   \
    } } while (0)

__global__ __launch_bounds__(64 * WAVES) void matcher_topk_kernel(
    const float* __restrict__ pred_box,  // [B, NP, 4]
    const float* __restrict__ gt_box,    // [B, NG, 4]
    int* __restrict__ out_pred,          // [B, NG*TOPK]
    int* __restrict__ out_gt,            // [B, NG*TOPK]
    int B, int NP, int NG)
{
    const int task = blockIdx.x;              // one block per (b, m)
    const int wid  = threadIdx.x >> 6;
    const int lane = threadIdx.x & 63;
    const int b = task / NG;
    const int m = task - b * NG;

    const float4 gb = ((const float4*)gt_box)[b * NG + m];
    const float g_area = (gb.z - gb.x) * (gb.w - gb.y);

    // sorted ascending top-5 keys; key = (cost_bits<<32) | pred_idx  (cost>=0)
    u64 k0 = ~0ULL, k1 = ~0ULL, k2 = ~0ULL, k3 = ~0ULL, k4 = ~0ULL;

    const float4* pbase = (const float4*)pred_box + (size_t)b * NP;
    const int stride = 64 * WAVES;

    int p = wid * 64 + lane;
    // unroll x2: two independent load+cost chains per iteration
    for (; p + stride < NP; p += 2 * stride) {
        const float4 pa = pbase[p];
        const float4 pc = pbase[p + stride];
        const u64 ka = make_key(pa, gb, g_area, p);
        const u64 kc = make_key(pc, gb, g_area, p + stride);
        INSERT(ka);
        INSERT(kc);
    }
    if (p < NP) {
        const float4 pa = pbase[p];
        const u64 ka = make_key(pa, gb, g_area, p);
        INSERT(ka);
    }

    // wave butterfly: merge sorted 5-lists across all 64 lanes
    #pragma unroll
    for (int off = 1; off < 64; off <<= 1) {
        const u64 b0 = __shfl_xor(k0, off);
        const u64 b1 = __shfl_xor(k1, off);
        const u64 b2 = __shfl_xor(k2, off);
        const u64 b3 = __shfl_xor(k3, off);
        const u64 b4 = __shfl_xor(k4, off);
        u64 m0 = k0 < b4 ? k0 : b4;
        u64 m1 = k1 < b3 ? k1 : b3;
        u64 m2 = k2 < b2 ? k2 : b2;
        u64 m3 = k3 < b1 ? k3 : b1;
        u64 m4 = k4 < b0 ? k4 : b0;
        CE(m0, m1); CE(m3, m4); CE(m2, m4); CE(m2, m3); CE(m1, m4);
        CE(m0, m3); CE(m0, m2); CE(m1, m3); CE(m1, m2);
        k0 = m0; k1 = m1; k2 = m2; k3 = m3; k4 = m4;
    }

    // cross-wave merge via LDS (4 sorted 5-lists -> final 5)
    __shared__ u64 lds[WAVES][TOPK];
    if (lane == 0) {
        lds[wid][0] = k0; lds[wid][1] = k1; lds[wid][2] = k2;
        lds[wid][3] = k3; lds[wid][4] = k4;
    }
    __syncthreads();

    if (threadIdx.x == 0) {
        int head[WAVES];
        #pragma unroll
        for (int w = 0; w < WAVES; ++w) head[w] = 0;
        const int base = task * TOPK;
        #pragma unroll
        for (int r = 0; r < TOPK; ++r) {
            u64 best = ~0ULL; int bw = 0;
            #pragma unroll
            for (int w = 0; w < WAVES; ++w) {
                const u64 v = lds[w][head[w]];
                if (v < best) { best = v; bw = w; }
            }
            head[bw]++;
            out_pred[base + r] = (int)(unsigned)(best & 0xFFFFFFFFu);
            out_gt[base + r]   = m;
        }
    }
}

extern "C" void kernel_launch(void* const* d_in, const int* in_sizes, int n_in,
                              void* d_out, int out_size, void* d_ws, size_t ws_size,
                              hipStream_t stream) {
    const float* pred_box = (const float*)d_in[0];   // [B, NP, 4]
    const float* gt_box   = (const float*)d_in[2];   // [B, NG, 4]

    const int NP = 5000;
    const int B  = in_sizes[1] / NP;                 // pred_obj is [B, NP]
    const int NG = in_sizes[3] / B;                  // gt_obj is [B, NG]

    int* out_pred = (int*)d_out;
    int* out_gt   = out_pred + B * NG * TOPK;

    const int total = B * NG;                        // one block per task
    hipLaunchKernelGGL(matcher_topk_kernel, dim3(total), dim3(64 * WAVES), 0, stream,
                       pred_box, gt_box, out_pred, out_gt, B, NP, NG);
}

// Round 3
// 40.438 us; speedup vs baseline: 1.2709x; 1.0510x over previous
//
#include <hip/hip_runtime.h>

#pragma clang fp contract(off)

typedef unsigned long long u64;

#define TOPK 5
#define WAVES 4   // waves per block; one block per gt-PAIR

// compare-exchange on u64 keys (ascending)
#define CE(x, y) do { if ((y) < (x)) { u64 _t = (x); (x) = (y); (y) = _t; } } while (0)

// sorted-insert of nk into ascending 5-list (strict <, preserves index tie-break)
#define INSERT(nk, k0, k1, k2, k3, k4)                          \
    do { if ((nk) < k4) {                                       \
        if ((nk) < k3) { k4 = k3;                               \
            if ((nk) < k2) { k3 = k2;                           \
                if ((nk) < k1) { k2 = k1;                       \
                    if ((nk) < k0) { k1 = k0; k0 = (nk); }      \
                    else           { k1 = (nk); }               \
                } else { k2 = (nk); }                           \
            } else { k3 = (nk); }                               \
        } else { k4 = (nk); }                                   \
    } } while (0)

// Markstein-refined division: rcp + NR + quotient correction.
// Correctly-rounded quotient in essentially all cases (round-to-nearest fma),
// ~6 ops instead of the ~11-instr exact div sequence.
__device__ __forceinline__ float fast_div(float a, float b) {
    float r = __builtin_amdgcn_rcpf(b);
    r = fmaf(fmaf(-b, r, 1.0f), r, r);   // Newton-Raphson: r ~0.5 ulp
    float q = a * r;
    q = fmaf(fmaf(-b, q, a), r, q);      // residual correction -> IEEE-rounded
    return q;
}

__device__ __forceinline__ u64 eval_key(const float4 pb, const float area_p,
                                        const float4 gb, const float g_area,
                                        const int p) {
    const float cost_bbox = fabsf(pb.x - gb.x) + fabsf(pb.y - gb.y)
                          + fabsf(pb.z - gb.z) + fabsf(pb.w - gb.w);
    // intersection
    const float ltx = fmaxf(pb.x, gb.x), lty = fmaxf(pb.y, gb.y);
    const float rbx = fminf(pb.z, gb.z), rby = fminf(pb.w, gb.w);
    const float iw = fmaxf(rbx - ltx, 0.0f), ih = fmaxf(rby - lty, 0.0f);
    const float inter = iw * ih;
    const float uni = area_p + g_area - inter;
    const float iou = fast_div(inter, uni);
    // enclosing box (rb_e - lt_e >= 0 always for valid xyxy -> clip is identity)
    const float ex1 = fminf(pb.x, gb.x), ey1 = fminf(pb.y, gb.y);
    const float ex2 = fmaxf(pb.z, gb.z), ey2 = fmaxf(pb.w, gb.w);
    const float area_e = (ex2 - ex1) * (ey2 - ey1);
    const float giou = iou - fast_div(area_e - uni, area_e);
    const float cost = cost_bbox + (1.0f - giou);
    return ((u64)__float_as_uint(cost) << 32) | (unsigned)p;
}

__global__ __launch_bounds__(64 * WAVES) void matcher_topk_kernel(
    const float* __restrict__ pred_box,  // [B, NP, 4]
    const float* __restrict__ gt_box,    // [B, NG, 4]
    int* __restrict__ out_pred,          // [B, NG*TOPK]
    int* __restrict__ out_gt,            // [B, NG*TOPK]
    int B, int NP, int NG)
{
    const int pairsPerB = (NG + 1) >> 1;
    const int tp = blockIdx.x;               // one block per (b, gt-pair)
    const int b  = tp / pairsPerB;
    const int j  = tp - b * pairsPerB;
    const int m0 = 2 * j;
    const int m1 = m0 + 1;
    const bool has1 = (m1 < NG);

    const int wid  = threadIdx.x >> 6;
    const int lane = threadIdx.x & 63;

    const float4 gb0 = ((const float4*)gt_box)[b * NG + m0];
    const float4 gb1 = ((const float4*)gt_box)[b * NG + (has1 ? m1 : m0)];
    const float ga0 = (gb0.z - gb0.x) * (gb0.w - gb0.y);
    const float ga1 = (gb1.z - gb1.x) * (gb1.w - gb1.y);

    // two independent sorted top-5 key sets (gt0 -> a*, gt1 -> c*)
    u64 a0 = ~0ULL, a1 = ~0ULL, a2 = ~0ULL, a3 = ~0ULL, a4 = ~0ULL;
    u64 c0 = ~0ULL, c1 = ~0ULL, c2 = ~0ULL, c3 = ~0ULL, c4 = ~0ULL;

    const float4* pbase = (const float4*)pred_box + (size_t)b * NP;

    int p = threadIdx.x;
    // unroll x2 on preds; each pred load feeds BOTH gts (4 independent chains)
    for (; p + 256 < NP; p += 512) {
        const float4 pA = pbase[p];
        const float4 pB = pbase[p + 256];
        const float apA = (pA.z - pA.x) * (pA.w - pA.y);
        const float apB = (pB.z - pB.x) * (pB.w - pB.y);
        const u64 kA0 = eval_key(pA, apA, gb0, ga0, p);
        const u64 kB0 = eval_key(pB, apB, gb0, ga0, p + 256);
        const u64 kA1 = eval_key(pA, apA, gb1, ga1, p);
        const u64 kB1 = eval_key(pB, apB, gb1, ga1, p + 256);
        INSERT(kA0, a0, a1, a2, a3, a4);
        INSERT(kB0, a0, a1, a2, a3, a4);
        INSERT(kA1, c0, c1, c2, c3, c4);
        INSERT(kB1, c0, c1, c2, c3, c4);
    }
    if (p < NP) {
        const float4 pA = pbase[p];
        const float apA = (pA.z - pA.x) * (pA.w - pA.y);
        const u64 kA0 = eval_key(pA, apA, gb0, ga0, p);
        const u64 kA1 = eval_key(pA, apA, gb1, ga1, p);
        INSERT(kA0, a0, a1, a2, a3, a4);
        INSERT(kA1, c0, c1, c2, c3, c4);
    }

    // wave butterfly: merge sorted 5-lists across 64 lanes, both sets interleaved
    #pragma unroll
    for (int off = 1; off < 64; off <<= 1) {
        const u64 sa0 = __shfl_xor(a0, off);
        const u64 sa1 = __shfl_xor(a1, off);
        const u64 sa2 = __shfl_xor(a2, off);
        const u64 sa3 = __shfl_xor(a3, off);
        const u64 sa4 = __shfl_xor(a4, off);
        const u64 sc0 = __shfl_xor(c0, off);
        const u64 sc1 = __shfl_xor(c1, off);
        const u64 sc2 = __shfl_xor(c2, off);
        const u64 sc3 = __shfl_xor(c3, off);
        const u64 sc4 = __shfl_xor(c4, off);

        u64 x0 = a0 < sa4 ? a0 : sa4;
        u64 x1 = a1 < sa3 ? a1 : sa3;
        u64 x2 = a2 < sa2 ? a2 : sa2;
        u64 x3 = a3 < sa1 ? a3 : sa1;
        u64 x4 = a4 < sa0 ? a4 : sa0;
        CE(x0, x1); CE(x3, x4); CE(x2, x4); CE(x2, x3); CE(x1, x4);
        CE(x0, x3); CE(x0, x2); CE(x1, x3); CE(x1, x2);
        a0 = x0; a1 = x1; a2 = x2; a3 = x3; a4 = x4;

        u64 y0 = c0 < sc4 ? c0 : sc4;
        u64 y1 = c1 < sc3 ? c1 : sc3;
        u64 y2 = c2 < sc2 ? c2 : sc2;
        u64 y3 = c3 < sc1 ? c3 : sc1;
        u64 y4 = c4 < sc0 ? c4 : sc0;
        CE(y0, y1); CE(y3, y4); CE(y2, y4); CE(y2, y3); CE(y1, y4);
        CE(y0, y3); CE(y0, y2); CE(y1, y3); CE(y1, y2);
        c0 = y0; c1 = y1; c2 = y2; c3 = y3; c4 = y4;
    }

    // cross-wave merge via LDS (per gt: 4 sorted 5-lists -> final 5)
    __shared__ u64 lds[2][WAVES][TOPK];
    if (lane == 0) {
        lds[0][wid][0] = a0; lds[0][wid][1] = a1; lds[0][wid][2] = a2;
        lds[0][wid][3] = a3; lds[0][wid][4] = a4;
        lds[1][wid][0] = c0; lds[1][wid][1] = c1; lds[1][wid][2] = c2;
        lds[1][wid][3] = c3; lds[1][wid][4] = c4;
    }
    __syncthreads();

    if (threadIdx.x < 2) {
        const int which = threadIdx.x;
        if (which == 0 || has1) {
            const int m = m0 + which;
            int head[WAVES];
            #pragma unroll
            for (int w = 0; w < WAVES; ++w) head[w] = 0;
            const int base = (b * NG + m) * TOPK;
            #pragma unroll
            for (int r = 0; r < TOPK; ++r) {
                u64 best = ~0ULL; int bw = 0;
                #pragma unroll
                for (int w = 0; w < WAVES; ++w) {
                    const u64 v = lds[which][w][head[w]];
                    if (v < best) { best = v; bw = w; }
                }
                head[bw]++;
                out_pred[base + r] = (int)(unsigned)(best & 0xFFFFFFFFu);
                out_gt[base + r]   = m;
            }
        }
    }
}

extern "C" void kernel_launch(void* const* d_in, const int* in_sizes, int n_in,
                              void* d_out, int out_size, void* d_ws, size_t ws_size,
                              hipStream_t stream) {
    const float* pred_box = (const float*)d_in[0];   // [B, NP, 4]
    const float* gt_box   = (const float*)d_in[2];   // [B, NG, 4]

    const int NP = 5000;
    const int B  = in_sizes[1] / NP;                 // pred_obj is [B, NP]
    const int NG = in_sizes[3] / B;                  // gt_obj is [B, NG]

    int* out_pred = (int*)d_out;
    int* out_gt   = out_pred + B * NG * TOPK;

    const int pairsPerB = (NG + 1) >> 1;
    const int blocks = B * pairsPerB;                // one block per gt-pair
    hipLaunchKernelGGL(matcher_topk_kernel, dim3(blocks), dim3(64 * WAVES), 0, stream,
                       pred_box, gt_box, out_pred, out_gt, B, NP, NG);
}